// Round 4
// baseline (534.592 us; speedup 1.0000x reference)
//
#include <hip/hip_runtime.h>
#include <hip/hip_cooperative_groups.h>

namespace cg = cooperative_groups;

#define D 1024
#define NB 8
#define T 4096

typedef float fvec4 __attribute__((ext_vector_type(4)));

// ===================== fused persistent cooperative kernel =====================
// Stage geometry (512 blocks x 256 threads, 2 blocks/CU):
//  S1 leaves_partial: 512 blocks (b,leaf,tc) -> lpart
//  S2 leaf gemm  (MODE0): 8 nodes x 32 kc (KCH=64)  -> gA   [256 blocks]
//  S3 level2     (MODE1): 4 nodes x 64 kc (KCH=32)  -> gB   [256 blocks]
//  S4 level1     (MODE1): 2 nodes x 128 kc (KCH=16) -> gA   [256 blocks]
//  S5 level0     (MODE1): 1 node x 256 kc (KCH=8)   -> gB   [256 blocks]
//  S6 root gate: 512 blocks (b, 16-col group), KC=256 partial sum
//  S7 add+LN: 512 blocks x 64 rows, wave-per-row

template <int KCH, int NKC, int KCPREV, int MODE>
__device__ __forceinline__ void tree_stage(int bid, int tid,
                                           const float* __restrict__ gprev,
                                           const float* __restrict__ W,
                                           const float* __restrict__ bias,
                                           const float* __restrict__ bt,
                                           float* __restrict__ gout,
                                           int node_base, int prev_base,
                                           float* fs) {
    int node = bid / NKC;
    int kc = bid % NKC;
    int k0 = kc * KCH;

    for (int idx = tid; idx < KCH * 8; idx += 256) {
        int kk = idx % KCH;
        int b = idx / KCH;
        int k = k0 + kk;
        int col = k & 1023;
        float v;
        if (MODE == 0) {
            float p = 0.f;
#pragma unroll
            for (int tc = 0; tc < 8; ++tc)
                p += gprev[(size_t)(((b * 8 + node) * 8 + tc)) * D + col];
            v = p * (1.0f / 256.0f);
        } else {
            int src = 2 * node + (k >> 10);
            float p = bias[(size_t)(prev_base + src) * D + col];
#pragma unroll 16
            for (int kcp = 0; kcp < KCPREV; ++kcp)
                p += gprev[(size_t)((src * KCPREV + kcp) * 8 + b) * D + col];
            float u = p - bt[(size_t)(prev_base + src) * D + col];
            v = (u > 0.0f) ? p : 0.0f;
        }
        fs[kk * 8 + b] = v;
    }
    __syncthreads();

    // each thread: 4 cols (float4), all 8 batch rows
    const fvec4* Wp = (const fvec4*)W + (size_t)(node_base + node) * 2048 * 256 +
                      (size_t)k0 * 256 + tid;
    fvec4 acc[8];
#pragma unroll
    for (int b = 0; b < 8; ++b) acc[b] = (fvec4){0.f, 0.f, 0.f, 0.f};
#pragma unroll 8
    for (int kk = 0; kk < KCH; ++kk) {
        fvec4 w = __builtin_nontemporal_load(Wp + (size_t)kk * 256);
#pragma unroll
        for (int b = 0; b < 8; ++b) acc[b] += w * fs[kk * 8 + b];
    }
    fvec4* op = (fvec4*)gout + (size_t)((node * NKC + kc) * 8) * 256 + tid;
#pragma unroll
    for (int b = 0; b < 8; ++b) op[(size_t)b * 256] = acc[b];
}

__global__ void __launch_bounds__(256, 2) fused_all(const float* __restrict__ x,
                                                    const float* __restrict__ W,
                                                    const float* __restrict__ bias,
                                                    const float* __restrict__ bt,
                                                    const float* __restrict__ lw,
                                                    const float* __restrict__ lb,
                                                    float* __restrict__ out,
                                                    float* __restrict__ lpart,
                                                    float* __restrict__ gA,
                                                    float* __restrict__ gB,
                                                    float* __restrict__ root) {
    cg::grid_group grid = cg::this_grid();
    __shared__ float smem[512];
    int bid = blockIdx.x;
    int tid = threadIdx.x;

    // ---- S1: leaf partial sums (rows 0..2047 of each batch) ----
    {
        int b = bid >> 6, leaf = (bid >> 3) & 7, tc = bid & 7;
        const fvec4* xp = (const fvec4*)x;
        size_t base = ((size_t)(b * T + leaf * 256 + tc * 32)) * 256 + tid;
        fvec4 acc = {0.f, 0.f, 0.f, 0.f};
#pragma unroll 8
        for (int tt = 0; tt < 32; ++tt)
            acc += __builtin_nontemporal_load(xp + base + (size_t)tt * 256);
        ((fvec4*)lpart)[(size_t)((b * 8 + leaf) * 8 + tc) * 256 + tid] = acc;
    }
    grid.sync();

    // ---- S2: leaf level (nodes 7..14), avg fused in staging ----
    if (bid < 256)
        tree_stage<64, 32, 8, 0>(bid, tid, lpart, W, bias, bt, gA, 7, 0, smem);
    grid.sync();

    // ---- S3: level 2 (nodes 3..6) ----
    if (bid < 256)
        tree_stage<32, 64, 32, 1>(bid, tid, gA, W, bias, bt, gB, 3, 7, smem);
    grid.sync();

    // ---- S4: level 1 (nodes 1..2) ----
    if (bid < 256)
        tree_stage<16, 128, 64, 1>(bid, tid, gB, W, bias, bt, gA, 1, 3, smem);
    grid.sync();

    // ---- S5: level 0 (node 0) ----
    if (bid < 256)
        tree_stage<8, 256, 128, 1>(bid, tid, gA, W, bias, bt, gB, 0, 1, smem);
    grid.sync();

    // ---- S6: root gate: sum 256 k-partials, bias, spike ----
    {
        int b = bid >> 6;
        int colg = bid & 63;
        int c = tid & 15, s = tid >> 4;
        int col = colg * 16 + c;
        float p = 0.f;
#pragma unroll
        for (int kc = s; kc < 256; kc += 16)
            p += gB[(size_t)(kc * 8 + b) * D + col];
        smem[s * 16 + c] = p;
        __syncthreads();
        if (tid < 16) {
            int col2 = colg * 16 + tid;
            float tot = bias[col2];
#pragma unroll
            for (int ss = 0; ss < 16; ++ss) tot += smem[ss * 16 + tid];
            float u = tot - bt[col2];
            root[b * D + col2] = (u > 0.0f) ? tot : 0.0f;
        }
    }
    grid.sync();

    // ---- S7: out = layernorm(root[b] + x[row]), wave-per-row ----
    {
        int wv = tid >> 6, lane = tid & 63;
        int b = bid >> 6;
        const fvec4* xp = (const fvec4*)x;
        const fvec4* rp = (const fvec4*)root + b * 256;
        const fvec4* lwp = (const fvec4*)lw;
        const fvec4* lbp = (const fvec4*)lb;
        fvec4 rv[4], lwv[4], lbv[4];
#pragma unroll
        for (int j = 0; j < 4; ++j) {
            rv[j] = rp[lane * 4 + j];
            lwv[j] = lwp[lane * 4 + j];
            lbv[j] = lbp[lane * 4 + j];
        }
        for (int i = 0; i < 16; ++i) {
            int row = bid * 64 + i * 4 + wv;
            fvec4 v[4];
            float s = 0.f, q = 0.f;
#pragma unroll
            for (int j = 0; j < 4; ++j) {
                fvec4 xv = __builtin_nontemporal_load(xp + (size_t)row * 256 + lane * 4 + j);
                v[j] = xv + rv[j];
                s += v[j].x + v[j].y + v[j].z + v[j].w;
                q += v[j].x * v[j].x + v[j].y * v[j].y + v[j].z * v[j].z + v[j].w * v[j].w;
            }
#pragma unroll
            for (int off = 32; off; off >>= 1) {
                s += __shfl_xor(s, off);
                q += __shfl_xor(q, off);
            }
            float mean = s * (1.0f / D);
            float var = q * (1.0f / D) - mean * mean;
            float rstd = rsqrtf(var + 1e-5f);
            fvec4* op = (fvec4*)out + (size_t)row * 256 + lane * 4;
#pragma unroll
            for (int j = 0; j < 4; ++j) {
                fvec4 o = (v[j] - mean) * rstd * lwv[j] + lbv[j];
                __builtin_nontemporal_store(o, op + j);
            }
        }
    }
}

// ===================== fallback path (proven R3 kernels) =====================

__global__ void __launch_bounds__(256) leaves_partial(const float* __restrict__ x,
                                                      float* __restrict__ lpart) {
    int b = blockIdx.x, leaf = blockIdx.y, tc = blockIdx.z;
    int tid = threadIdx.x;
    const float4* xp = (const float4*)x;
    size_t base = ((size_t)b * T + (size_t)leaf * 256 + (size_t)tc * 32) * (D / 4) + tid;
    float4 acc = {0.f, 0.f, 0.f, 0.f};
#pragma unroll 8
    for (int tt = 0; tt < 32; ++tt) {
        float4 v = xp[base + (size_t)tt * (D / 4)];
        acc.x += v.x; acc.y += v.y; acc.z += v.z; acc.w += v.w;
    }
    ((float4*)lpart)[(((b * 8 + leaf) * 8 + tc) * (D / 4)) + tid] = acc;
}

template <int KCH, int KCPREV, int MODE>
__global__ void __launch_bounds__(256) tree_gemm(const float* __restrict__ gprev,
                                                 const float* __restrict__ W,
                                                 const float* __restrict__ bias,
                                                 const float* __restrict__ bt,
                                                 float* __restrict__ gout,
                                                 int node_base, int prev_base) {
    int node = blockIdx.x;
    int c0 = blockIdx.y * 256;
    int k0 = blockIdx.z * KCH;
    int tid = threadIdx.x;
    int nkc = gridDim.z;

    __shared__ float fs[KCH][8];
    for (int idx = tid; idx < KCH * 8; idx += 256) {
        int kk = idx % KCH;
        int b = idx / KCH;
        int k = k0 + kk;
        int col = k & 1023;
        float v;
        if (MODE == 0) {
            float p = 0.f;
#pragma unroll
            for (int tc = 0; tc < 8; ++tc)
                p += gprev[(((size_t)(b * 8 + node)) * 8 + tc) * D + col];
            v = p * (1.0f / 256.0f);
        } else {
            int src = 2 * node + (k >> 10);
            float p = bias[(size_t)(prev_base + src) * D + col];
#pragma unroll
            for (int kc = 0; kc < KCPREV; ++kc)
                p += gprev[(((size_t)src * KCPREV + kc) * 8 + b) * D + col];
            float u = p - bt[(size_t)(prev_base + src) * D + col];
            v = (u > 0.0f) ? p : 0.0f;
        }
        fs[kk][b] = v;
    }
    __syncthreads();

    int col = c0 + tid;
    const float* Wp = W + (size_t)(node_base + node) * 2048 * D + (size_t)k0 * D + col;
    float acc0 = 0.f, acc1 = 0.f, acc2 = 0.f, acc3 = 0.f;
    float acc4 = 0.f, acc5 = 0.f, acc6 = 0.f, acc7 = 0.f;
#pragma unroll 8
    for (int kk = 0; kk < KCH; ++kk) {
        float w = Wp[(size_t)kk * D];
        float4 f0 = *(const float4*)&fs[kk][0];
        float4 f1 = *(const float4*)&fs[kk][4];
        acc0 += f0.x * w; acc1 += f0.y * w; acc2 += f0.z * w; acc3 += f0.w * w;
        acc4 += f1.x * w; acc5 += f1.y * w; acc6 += f1.z * w; acc7 += f1.w * w;
    }
    size_t gb = ((size_t)(node * nkc + blockIdx.z) * 8) * D + col;
    gout[gb + 0 * D] = acc0; gout[gb + 1 * D] = acc1;
    gout[gb + 2 * D] = acc2; gout[gb + 3 * D] = acc3;
    gout[gb + 4 * D] = acc4; gout[gb + 5 * D] = acc5;
    gout[gb + 6 * D] = acc6; gout[gb + 7 * D] = acc7;
}

template <int KC>
__global__ void __launch_bounds__(256) root_gate(const float* __restrict__ gpart,
                                                 const float* __restrict__ bias,
                                                 const float* __restrict__ bt,
                                                 float* __restrict__ root) {
    int gid = blockIdx.x * 256 + threadIdx.x;
    int col = gid & 1023;
    int b = gid >> 10;
    float p = bias[col];
#pragma unroll
    for (int kc = 0; kc < KC; ++kc)
        p += gpart[((size_t)kc * 8 + b) * D + col];
    float u = p - bt[col];
    root[gid] = (u > 0.0f) ? p : 0.0f;
}

__global__ void __launch_bounds__(256) add_ln(const float* __restrict__ x,
                                              const float* __restrict__ root,
                                              const float* __restrict__ lw,
                                              const float* __restrict__ lb,
                                              float* __restrict__ out) {
    int row = blockIdx.x;
    int b = row >> 12;
    int tid = threadIdx.x;
    const fvec4* xr = (const fvec4*)x + (size_t)row * (D / 4);
    float4 r = ((const float4*)root)[b * (D / 4) + tid];
    fvec4 vv = __builtin_nontemporal_load(xr + tid);
    float4 v;
    v.x = vv.x + r.x; v.y = vv.y + r.y; v.z = vv.z + r.z; v.w = vv.w + r.w;

    float s = v.x + v.y + v.z + v.w;
    float q = v.x * v.x + v.y * v.y + v.z * v.z + v.w * v.w;
#pragma unroll
    for (int off = 32; off; off >>= 1) {
        s += __shfl_down(s, off);
        q += __shfl_down(q, off);
    }
    __shared__ float ss[4], sq[4];
    int wave = tid >> 6, lane = tid & 63;
    if (lane == 0) { ss[wave] = s; sq[wave] = q; }
    __syncthreads();
    s = ss[0] + ss[1] + ss[2] + ss[3];
    q = sq[0] + sq[1] + sq[2] + sq[3];

    float mean = s * (1.0f / D);
    float var = q * (1.0f / D) - mean * mean;
    float rstd = rsqrtf(var + 1e-5f);

    float4 w4 = ((const float4*)lw)[tid];
    float4 b4 = ((const float4*)lb)[tid];
    fvec4 o;
    o.x = (v.x - mean) * rstd * w4.x + b4.x;
    o.y = (v.y - mean) * rstd * w4.y + b4.y;
    o.z = (v.z - mean) * rstd * w4.z + b4.z;
    o.w = (v.w - mean) * rstd * w4.w + b4.w;
    __builtin_nontemporal_store(o, (fvec4*)out + (size_t)row * (D / 4) + tid);
}

// ===================== launcher =====================

extern "C" void kernel_launch(void* const* d_in, const int* in_sizes, int n_in,
                              void* d_out, int out_size, void* d_ws, size_t ws_size,
                              hipStream_t stream) {
    const float* x    = (const float*)d_in[0];
    const float* W    = (const float*)d_in[1];
    const float* bias = (const float*)d_in[2];
    const float* bt   = (const float*)d_in[3];
    const float* lw   = (const float*)d_in[4];
    const float* lb   = (const float*)d_in[5];
    float* out = (float*)d_out;

    float* ws = (float*)d_ws;

    // coop layout: lpart 512K | gA 2M | gB 2M | root 8K  (floats)
    const size_t LPART = 512 * 1024;
    const size_t GBUF = 2 * 1024 * 1024;
    float* lpart = ws;
    float* gA = lpart + LPART;
    float* gB = gA + GBUF;
    float* root = gB + GBUF;
    size_t need_bytes = (LPART + 2 * GBUF + 8192) * sizeof(float);

    bool coop_ok = false;
    if (ws_size >= need_bytes) {
        void* args[] = {(void*)&x, (void*)&W, (void*)&bias, (void*)&bt,
                        (void*)&lw, (void*)&lb, (void*)&out,
                        (void*)&lpart, (void*)&gA, (void*)&gB, (void*)&root};
        hipError_t err = hipLaunchCooperativeKernel((void*)fused_all, dim3(512),
                                                    dim3(256), args, 0, stream);
        coop_ok = (err == hipSuccess);
    }

    if (!coop_ok) {
        // fallback: proven 7-dispatch path (R3 layout, ~8.5 MB)
        float* f_lpart = ws;
        float* f_gA = f_lpart + 524288;
        float* f_gB = f_gA + 1048576;
        float* f_root = f_gB + 524288;

        leaves_partial<<<dim3(8, 8, 8), 256, 0, stream>>>(x, f_lpart);
        tree_gemm<128, 8, 0><<<dim3(8, 4, 16), 256, 0, stream>>>(
            f_lpart, W, bias, bt, f_gA, 7, 0);
        tree_gemm<128, 16, 1><<<dim3(4, 4, 16), 256, 0, stream>>>(
            f_gA, W, bias, bt, f_gB, 3, 7);
        tree_gemm<64, 16, 1><<<dim3(2, 4, 32), 256, 0, stream>>>(
            f_gB, W, bias, bt, f_gA, 1, 3);
        tree_gemm<32, 32, 1><<<dim3(1, 4, 64), 256, 0, stream>>>(
            f_gA, W, bias, bt, f_gB, 0, 1);
        root_gate<64><<<32, 256, 0, stream>>>(f_gB, bias, bt, f_root);
        add_ln<<<NB * T, 256, 0, stream>>>(x, f_root, lw, lb, out);
    }
}

// Round 5
// 108.055 us; speedup vs baseline: 4.9474x; 4.9474x over previous
//
#include <hip/hip_runtime.h>

#define D 1024
#define NB 8
#define T 4096

typedef float fvec4 __attribute__((ext_vector_type(4)));

// ---------------- leaves: partial sums over t-chunks of 32 ----------------
// lpart[b][leaf][tc][col] = sum of 32 rows (rows 0..2047 of each batch)
__global__ void __launch_bounds__(256, 2) leaves_partial(const float* __restrict__ x,
                                                         float* __restrict__ lpart) {
    int bid = blockIdx.x;                  // 512 blocks
    int b = bid >> 6, leaf = (bid >> 3) & 7, tc = bid & 7;
    int tid = threadIdx.x;
    const fvec4* xp = (const fvec4*)x;
    size_t base = ((size_t)(b * T + leaf * 256 + tc * 32)) * 256 + tid;
    fvec4 acc = {0.f, 0.f, 0.f, 0.f};
#pragma unroll 8
    for (int tt = 0; tt < 32; ++tt)
        acc += xp[base + (size_t)tt * 256];
    ((fvec4*)lpart)[(size_t)((b * 8 + leaf) * 8 + tc) * 256 + tid] = acc;
}

// ---------------- fused tree-level GEMM (float4 W loads) ------------------
// grid = NODES*NKC blocks; block (node,kc) computes gout[node][kc][b][col]
// = sum_{k in chunk} fused[b][k] * W[node_base+node][k][col], 4 cols/thread.
// MODE 0: stage = mean of 8 lpart partials. MODE 1: stage = gate(reduce prev).
template <int KCH, int NKC, int KCPREV, int MODE>
__global__ void __launch_bounds__(256, 2) tree_gemm(const float* __restrict__ gprev,
                                                    const float* __restrict__ W,
                                                    const float* __restrict__ bias,
                                                    const float* __restrict__ bt,
                                                    float* __restrict__ gout,
                                                    int node_base, int prev_base) {
    int bid = blockIdx.x;
    int node = bid / NKC;
    int kc = bid % NKC;
    int k0 = kc * KCH;
    int tid = threadIdx.x;

    __shared__ float fs[KCH * 8];
    for (int idx = tid; idx < KCH * 8; idx += 256) {
        int kk = idx % KCH;
        int b = idx / KCH;
        int k = k0 + kk;
        int col = k & 1023;
        float v;
        if (MODE == 0) {
            float p = 0.f;
#pragma unroll
            for (int tc = 0; tc < 8; ++tc)
                p += gprev[(size_t)((b * 8 + node) * 8 + tc) * D + col];
            v = p * (1.0f / 256.0f);
        } else {
            int src = 2 * node + (k >> 10);
            float p = bias[(size_t)(prev_base + src) * D + col];
#pragma unroll 16
            for (int kcp = 0; kcp < KCPREV; ++kcp)
                p += gprev[(size_t)((src * KCPREV + kcp) * 8 + b) * D + col];
            float u = p - bt[(size_t)(prev_base + src) * D + col];
            v = (u > 0.0f) ? p : 0.0f;
        }
        fs[kk * 8 + b] = v;
    }
    __syncthreads();

    const fvec4* Wp = (const fvec4*)W +
                      ((size_t)(node_base + node) * 2048 + (size_t)k0) * 256 + tid;
    fvec4 acc[8];
#pragma unroll
    for (int b = 0; b < 8; ++b) acc[b] = (fvec4){0.f, 0.f, 0.f, 0.f};
#pragma unroll 4
    for (int kk = 0; kk < KCH; ++kk) {
        fvec4 w = __builtin_nontemporal_load(Wp + (size_t)kk * 256);
#pragma unroll
        for (int b = 0; b < 8; ++b) acc[b] += w * fs[kk * 8 + b];
    }
    fvec4* op = (fvec4*)gout + (size_t)((node * NKC + kc) * 8) * 256 + tid;
#pragma unroll
    for (int b = 0; b < 8; ++b) op[(size_t)b * 256] = acc[b];
}

// ---------------- root: reduce level-0 partials, bias, gate ---------------
// gpart = [KC kc][8 b][1024 col]; 512 blocks: (b, 16-col group)
template <int KC>
__global__ void __launch_bounds__(256, 2) root_gate(const float* __restrict__ gpart,
                                                    const float* __restrict__ bias,
                                                    const float* __restrict__ bt,
                                                    float* __restrict__ root) {
    int b = blockIdx.x >> 6;
    int colg = blockIdx.x & 63;
    int tid = threadIdx.x;
    int c = tid & 15, s = tid >> 4;
    int col = colg * 16 + c;
    float p = 0.f;
#pragma unroll 4
    for (int kc = s; kc < KC; kc += 16)
        p += gpart[(size_t)(kc * 8 + b) * D + col];
    __shared__ float sm[256];
    sm[s * 16 + c] = p;
    __syncthreads();
    if (tid < 16) {
        int col2 = colg * 16 + tid;
        float tot = bias[col2];
#pragma unroll
        for (int ss = 0; ss < 16; ++ss) tot += sm[ss * 16 + tid];
        float u = tot - bt[col2];
        root[b * D + col2] = (u > 0.0f) ? tot : 0.0f;
    }
}

// ---------------- final: out = layernorm(root[b] + x[row]) ----------------
// 8192 blocks x 4 rows; one 64-lane wave per row, no __syncthreads.
__global__ void __launch_bounds__(256, 2) add_ln(const float* __restrict__ x,
                                                 const float* __restrict__ root,
                                                 const float* __restrict__ lw,
                                                 const float* __restrict__ lb,
                                                 float* __restrict__ out) {
    int tid = threadIdx.x;
    int wv = tid >> 6, lane = tid & 63;
    int row = blockIdx.x * 4 + wv;
    int b = row >> 12;
    const fvec4* xp = (const fvec4*)x;
    const fvec4* rp = (const fvec4*)root + b * 256;
    const fvec4* lwp = (const fvec4*)lw;
    const fvec4* lbp = (const fvec4*)lb;

    fvec4 rv[4], lwv[4], lbv[4], v[4];
#pragma unroll
    for (int j = 0; j < 4; ++j) {
        rv[j] = rp[j * 64 + lane];
        lwv[j] = lwp[j * 64 + lane];
        lbv[j] = lbp[j * 64 + lane];
    }
    float s = 0.f, q = 0.f;
#pragma unroll
    for (int j = 0; j < 4; ++j) {
        fvec4 xv = xp[(size_t)row * 256 + j * 64 + lane];
        v[j] = xv + rv[j];
        s += v[j].x + v[j].y + v[j].z + v[j].w;
        q += v[j].x * v[j].x + v[j].y * v[j].y + v[j].z * v[j].z + v[j].w * v[j].w;
    }
#pragma unroll
    for (int off = 32; off; off >>= 1) {
        s += __shfl_xor(s, off);
        q += __shfl_xor(q, off);
    }
    float mean = s * (1.0f / D);
    float var = q * (1.0f / D) - mean * mean;
    float rstd = rsqrtf(var + 1e-5f);
    fvec4* op = (fvec4*)out + (size_t)row * 256;
#pragma unroll
    for (int j = 0; j < 4; ++j) {
        fvec4 o = (v[j] - mean) * rstd * lwv[j] + lbv[j];
        __builtin_nontemporal_store(o, op + j * 64 + lane);
    }
}

// ===================== launcher =====================

extern "C" void kernel_launch(void* const* d_in, const int* in_sizes, int n_in,
                              void* d_out, int out_size, void* d_ws, size_t ws_size,
                              hipStream_t stream) {
    const float* x    = (const float*)d_in[0];
    const float* W    = (const float*)d_in[1];
    const float* bias = (const float*)d_in[2];
    const float* bt   = (const float*)d_in[3];
    const float* lw   = (const float*)d_in[4];
    const float* lb   = (const float*)d_in[5];
    float* out = (float*)d_out;

    float* ws = (float*)d_ws;
    float* lpart = ws;                    // 8*8*8*1024          = 524288 floats
    float* gA    = lpart + 524288;        // 8n*32kc*8b*1024     = 2097152
    float* gB    = gA + 2097152;          // up to 256kc*8b*1024 = 2097152
    float* root  = gB + 2097152;          // 8*1024

    // 1) leaf partial sums (rows 0..2047 of each batch)
    leaves_partial<<<512, 256, 0, stream>>>(x, lpart);

    // 2) tree levels, gate fused into consumer staging; 256 blocks each
    // leaf level (nodes 7..14): mean(lpart) -> gA  [8 nodes x 32 kc, KCH=64]
    tree_gemm<64, 32, 8, 0><<<256, 256, 0, stream>>>(lpart, W, bias, bt, gA, 7, 0);
    // level 2 (nodes 3..6): gate(gA, base 7) -> gB [4 x 64, KCH=32]
    tree_gemm<32, 64, 32, 1><<<256, 256, 0, stream>>>(gA, W, bias, bt, gB, 3, 7);
    // level 1 (nodes 1..2): gate(gB, base 3) -> gA [2 x 128, KCH=16]
    tree_gemm<16, 128, 64, 1><<<256, 256, 0, stream>>>(gB, W, bias, bt, gA, 1, 3);
    // level 0 (node 0): gate(gA, base 1) -> gB     [1 x 256, KCH=8]
    tree_gemm<8, 256, 128, 1><<<256, 256, 0, stream>>>(gA, W, bias, bt, gB, 0, 1);

    // 3) root = gate(bias0 + sum_kc gB, bt0)
    root_gate<256><<<512, 256, 0, stream>>>(gB, bias, bt, root);

    // 4) out = layernorm(root + x)
    add_ln<<<NB * T / 4, 256, 0, stream>>>(x, root, lw, lb, out);
}